// Round 6
// baseline (4288.957 us; speedup 1.0000x reference)
//
#include <hip/hip_runtime.h>
#include <math.h>

// ---------------------------------------------------------------------------
// Decoder: 3-layer LSTM + dot attention + MLP + CE loss.  B=16, T=257, H=1024.
// Round 10 (= round 9 + memory-level-parallelism fixes):
//   - recurrence: persistent kernel (256 WGs x 1024 thr, weights in VGPRs).
//     h stores: relaxed agent-scope atomic (write-through, nothing dirty in
//     L2). h loads: normal cached loads (LLC->L2 once per XCD). No per-step
//     fence (see round-8/9 argument: every h address is written once and
//     read once per launch; slots are 32KB-aligned; first read is strictly
//     after the producer's vmcnt(0)-drained store via the cache-bypassing
//     arrive-flag barrier).
//   - NEW: a-fragment loads are batched 12-deep (af[12] array + sched_barrier
//     between load loop and MFMA loop). Round 9's VGPR_Count=64 showed the
//     compiler was serializing load->MFMA pairs (48 VGPRs of weights left no
//     room); 12 serial L2/IF$ latencies ~= the missing ~5 us/step. Now needs
//     ~116 VGPRs (<=128 limit for 1024-thr WGs) with 12 loads in flight.
//   - NEW: dec_in token prefetched one step ahead (off the critical path).
//   - NEW: poll backoff s_sleep(2).
//   - epilogue: unchanged bf16 MFMA NT-GEMM pipeline.
// Workspace: 70.62 MB (< 76.15 MB known-safe).
// ---------------------------------------------------------------------------

namespace {
constexpr int TT = 257;
constexpr int BT = 4112;
constexpr int NSTEP = 259;
constexpr int NWG = 256;

// ushort (bf16) element offsets
constexpr size_t OFF_EMBB = 0;                    // [1024][512] (recurrence only)
constexpr size_t OFF_H0H  = 524288;               // [258][16][1024] (recurrence only)
constexpr size_t OFF_H1H  = 4751360;              // [258][16][1024] (recurrence only)
constexpr size_t OFF_H2H  = 8978432;              // [258][16][1024] (live into epilogue)
// epilogue aliases over embB+h0h+h1h (dead after recurrence):
constexpr size_t OFF_ENCB = 0;                    // [16][512][1024] = 8388608 <= 8978432
constexpr size_t OFF_ENCT = 13205504;             // [16][1024][512]
constexpr size_t OFF_W1B  = 21594112;             // [1024][2048]
constexpr size_t OFF_W2B  = 23691264;             // [1024][1024]
constexpr size_t OFF_SC   = 24739840;             // [16][257][512]
constexpr size_t OFF_CTX  = 26845184;             // [16][257][1024]
constexpr size_t OFF_HID  = 31055872;             // [4112][1024]
constexpr size_t OFF_LG   = OFF_SC;               // alias (sc+ctx dead at logits)
constexpr size_t END_BF   = 35266560;
// int region: dec_in[4112] dec_out[4112] hsrow[4112] pad | arrive[256*32]
constexpr size_t OFF_INT_BYTES = END_BF * 2;      // 70,533,120
constexpr int    ARRIVE_I0     = 12352;           // int index (128B aligned)
constexpr size_t TOTAL_BYTES   = OFF_INT_BYTES + (ARRIVE_I0 + 256 * 32 + 16) * 4;
constexpr unsigned SPIN_CAP    = 1u << 24;        // hang-breaker (legit wait << this)
}

typedef __attribute__((ext_vector_type(8))) short bf16x8;
typedef __attribute__((ext_vector_type(4))) float f32x4;

__device__ __forceinline__ float bf2f(ushort u) {
    union { unsigned int v; float f; } x; x.v = ((unsigned int)u) << 16; return x.f;
}
__device__ __forceinline__ ushort f2bf(float f) {
    union { float f; unsigned int v; } x; x.f = f;
    return (ushort)((x.v + 0x7fff + ((x.v >> 16) & 1)) >> 16);
}
__device__ __forceinline__ float sigm(float x) { return 1.f / (1.f + __expf(-x)); }

// ---------------------------------------------------------------------------
__global__ void k_fail(float* out) { out[0] = -123456.0f; }

// ---------------------------------------------------------------------------
// init: embB convert, h-history slot0 zeros, dec_in/dec_out/hsrow, flags, out.
// grid 256x256 = 65536 threads. Re-runs per replay (idempotent graph).
__global__ __launch_bounds__(256) void k_init(const int* __restrict__ tokens,
                                              const float* __restrict__ emb,
                                              ushort* __restrict__ wsb,
                                              float* __restrict__ out)
{
    int i = blockIdx.x * 256 + threadIdx.x;          // 0..65535
    int* dec_in  = (int*)((char*)wsb + OFF_INT_BYTES);
    int* dec_out = dec_in + 4112;
    int* hsrow   = dec_in + 8224;
    unsigned* flags = (unsigned*)(dec_in + ARRIVE_I0);
    {   // embB: 524288 elems = 65536 * 8
        size_t e = (size_t)i * 8;
        float4 a = *(const float4*)(emb + e);
        float4 b = *(const float4*)(emb + e + 4);
        uint4 o;
        o.x = (unsigned)f2bf(a.x) | ((unsigned)f2bf(a.y) << 16);
        o.y = (unsigned)f2bf(a.z) | ((unsigned)f2bf(a.w) << 16);
        o.z = (unsigned)f2bf(b.x) | ((unsigned)f2bf(b.y) << 16);
        o.w = (unsigned)f2bf(b.z) | ((unsigned)f2bf(b.w) << 16);
        *(uint4*)(wsb + OFF_EMBB + e) = o;
    }
    if (i < 16384) {                                  // slot 0 = initial zeros
        wsb[OFF_H0H + i] = 0; wsb[OFF_H1H + i] = 0; wsb[OFF_H2H + i] = 0;
    }
    if (i < 4112) {
        int t = i >> 4, b = i & 15;                   // t-major
        dec_in[i] = (t == 0) ? 1 : tokens[b * 256 + (t - 1)];
        int bb = i / 257, tt = i % 257;               // m-order (b-major)
        dec_out[i] = (tt < 256) ? tokens[bb * 256 + tt] : 2;
        hsrow[i] = (tt + 1) * 16 + bb;
    }
    if (i < 256 * 32 + 16) flags[i] = 0u;             // arrive[]
    if (i == 0) out[0] = 0.f;
}

// ---------------------------------------------------------------------------
// Persistent fused recurrence. 256 WGs x 1024 thr (16 waves).
// WG u owns units [4u,4u+4) of all 4 gates for all 3 cells. Wave w ->
// (cell, granule range); granule = one 16x16x32 MFMA over a 32-wide K chunk.
// Weights live in wreg[12] (bf16 B-fragments); a-fragments batched in af[12].
// Diagonal step d: cell0 t=d, cell1 t=d-1, cell2 t=d-2. Flat arrive-flag
// barrier per step; NO fence.
__global__ __launch_bounds__(1024, 4) void k_rec_persist(
    ushort* __restrict__ wsb,
    const float* __restrict__ Whh0, const float* __restrict__ Wih0,
    const float* __restrict__ Wih1, const float* __restrict__ Whh1,
    const float* __restrict__ Wih2, const float* __restrict__ Whh2,
    const float* __restrict__ bih0, const float* __restrict__ bhh0,
    const float* __restrict__ bih1, const float* __restrict__ bhh1,
    const float* __restrict__ bih2, const float* __restrict__ bhh2,
    const int* __restrict__ dec_in, unsigned* __restrict__ arrive)
{
    __shared__ float p[16][16][17];   // [wave][batch][tile-row], padded

    int tid = threadIdx.x;
    int u = blockIdx.x;                       // 0..255
    int w = tid >> 6, lane = tid & 63, l15 = lane & 15, quad = lane >> 4;

    // wave -> (cell, first granule, count).  cell0: 48 granules (hh0 32 + emb 16)
    // over waves 0-3 (12 each); cell1: 64 (ih1 32 + hh1 32) over waves 4-9
    // (11,11,11,11,10,10); cell2: same over waves 10-15.
    int cell, g0, gcnt;
    if (w < 4)       { cell = 0; g0 = w * 12; gcnt = 12; }
    else if (w < 10) { int wi = w - 4;  cell = 1;
                       g0 = (wi < 4) ? wi * 11 : 44 + (wi - 4) * 10;
                       gcnt = (wi < 4) ? 11 : 10; }
    else             { int wi = w - 10; cell = 2;
                       g0 = (wi < 4) ? wi * 11 : 44 + (wi - 4) * 10;
                       gcnt = (wi < 4) ? 11 : 10; }

    // weight row for tile-row l15: gate gt, unit-sub s4
    int gt = l15 >> 2, s4 = l15 & 3;
    size_t wrow = (size_t)(gt * 1024 + u * 4 + s4);

    // ---- prologue: load + convert this wave's weight fragments (once) ----
    bf16x8 wreg[12];
    #pragma unroll
    for (int gi = 0; gi < 12; ++gi) {
        if (gi < gcnt) {
            int g = g0 + gi;
            const float* src;
            if (cell == 0)
                src = (g < 32) ? Whh0 + wrow * 1024 + (size_t)g * 32
                               : Wih0 + wrow * 1536 + (size_t)(g - 32) * 32;
            else if (cell == 1)
                src = (g < 32) ? Wih1 + wrow * 1024 + (size_t)g * 32
                               : Whh1 + wrow * 1024 + (size_t)(g - 32) * 32;
            else
                src = (g < 32) ? Wih2 + wrow * 1024 + (size_t)g * 32
                               : Whh2 + wrow * 1024 + (size_t)(g - 32) * 32;
            src += quad * 8;
            float4 a = *(const float4*)src;
            float4 b = *(const float4*)(src + 4);
            bf16x8 v;
            v[0] = (short)f2bf(a.x); v[1] = (short)f2bf(a.y);
            v[2] = (short)f2bf(a.z); v[3] = (short)f2bf(a.w);
            v[4] = (short)f2bf(b.x); v[5] = (short)f2bf(b.y);
            v[6] = (short)f2bf(b.z); v[7] = (short)f2bf(b.w);
            wreg[gi] = v;
        }
    }

    // ---- elementwise thread state (tid<192): bias + c in registers ----
    int cellE = tid >> 6;                     // 0..2 for tid<192
    int sub = tid & 63, bE = sub & 15, sE = sub >> 4;
    int colE = u * 4 + sE;
    float bsum[4] = {0.f, 0.f, 0.f, 0.f};
    float cst = 0.f;
    ushort* hE = nullptr;
    int wloE = 0, whiE = 0;
    if (tid < 192) {
        const float* biE = (cellE == 0) ? bih0 : (cellE == 1) ? bih1 : bih2;
        const float* bhE = (cellE == 0) ? bhh0 : (cellE == 1) ? bhh1 : bhh2;
        #pragma unroll
        for (int gq = 0; gq < 4; ++gq)
            bsum[gq] = biE[gq * 1024 + colE] + bhE[gq * 1024 + colE];
        hE = wsb + ((cellE == 0) ? OFF_H0H : (cellE == 1) ? OFF_H1H : OFF_H2H);
        wloE = (cellE == 0) ? 0 : (cellE == 1) ? 4 : 10;
        whiE = (cellE == 0) ? 4 : (cellE == 1) ? 10 : 16;
    }

    ushort* h0h = wsb + OFF_H0H;
    ushort* h1h = wsb + OFF_H1H;
    ushort* h2h = wsb + OFF_H2H;
    const ushort* embB = wsb + OFF_EMBB;
    size_t aoff = (size_t)l15 * 1024 + quad * 8;

    // token prefetch (cell0 waves): tokv holds dec_in for the UPCOMING step
    int tokv = 0;
    if (cell == 0) tokv = dec_in[l15];        // t = 0

    for (int d = 0; d < NSTEP; ++d) {
        int t = d - cell;
        f32x4 acc = {0.f, 0.f, 0.f, 0.f};
        if (t >= 0 && t < TT) {
            const ushort* a0p;
            const ushort* a1p;
            if (cell == 0) {
                a0p = h0h + (size_t)t * 16384 + aoff;  // h0(t-1), slot0 = zeros
                int tok = tokv;
                a1p = embB + (size_t)tok * 512 + quad * 8;
                // prefetch next step's token (consumed after the barrier)
                int tn = (t + 1 < TT) ? (t + 1) : (TT - 1);
                tokv = dec_in[tn * 16 + l15];
            } else if (cell == 1) {
                a0p = h0h + (size_t)(t + 1) * 16384 + aoff;  // h0(t)
                a1p = h1h + (size_t)t * 16384 + aoff;        // h1(t-1)
            } else {
                a0p = h1h + (size_t)(t + 1) * 16384 + aoff;  // h1(t)
                a1p = h2h + (size_t)t * 16384 + aoff;        // h2(t-1)
            }
            // ---- batched loads: all 12 a-fragments in flight ----
            bf16x8 af[12];
            #pragma unroll
            for (int gi = 0; gi < 12; ++gi) {
                if (gi < gcnt) {
                    int g = g0 + gi;
                    af[gi] = (g < 32)
                        ? *(const bf16x8*)(a0p + (size_t)g * 32)
                        : *(const bf16x8*)(a1p + (size_t)(g - 32) * 32);
                }
            }
            __builtin_amdgcn_sched_barrier(0);   // keep loads hoisted above MFMAs
            #pragma unroll
            for (int gi = 0; gi < 12; ++gi) {
                if (gi < gcnt) {
                    acc = __builtin_amdgcn_mfma_f32_16x16x32_bf16(
                        af[gi], wreg[gi], acc, 0, 0, 0);
                }
            }
        }
        // C/D layout: col=lane&15 (tile row), row=quad*4+reg (batch)
        #pragma unroll
        for (int r = 0; r < 4; ++r) p[w][quad * 4 + r][l15] = acc[r];
        __syncthreads();

        if (tid < 192) {
            int tE = d - cellE;
            if (tE >= 0 && tE < TT) {
                float gv[4];
                #pragma unroll
                for (int gq = 0; gq < 4; ++gq) {
                    float a2 = bsum[gq];
                    for (int ww = wloE; ww < whiE; ++ww)
                        a2 += p[ww][bE][gq * 4 + sE];
                    gv[gq] = a2;
                }
                float ig = sigm(gv[0]), fg = sigm(gv[1]);
                float gg = tanhf(gv[2]), og = sigm(gv[3]);
                cst = fg * cst + ig * gg;
                ushort hus = f2bf(og * tanhf(cst));
                // pack 2 bf16 -> uint; even-sE threads store write-through
                unsigned hi = __shfl_down((unsigned)hus, 16, 64);
                if ((sE & 1) == 0) {
                    unsigned* hp = (unsigned*)(hE + (size_t)(tE + 1) * 16384
                                               + (size_t)bE * 1024 + colE);
                    __hip_atomic_store(hp, (unsigned)hus | (hi << 16),
                                       __ATOMIC_RELAXED, __HIP_MEMORY_SCOPE_AGENT);
                }
            }
        }

        // ---- flat grid barrier: arrive flags only, all-poll, NO fence ----
        asm volatile("s_waitcnt vmcnt(0)" ::: "memory");   // h stores acked @LLC
        __syncthreads();
        unsigned stamp = (unsigned)(d + 1);
        if (tid == 0)
            __hip_atomic_store(arrive + u * 32, stamp,
                               __ATOMIC_RELAXED, __HIP_MEMORY_SCOPE_AGENT);
        if (tid < 256) {
            unsigned spins = 0;
            while (__hip_atomic_load(arrive + tid * 32, __ATOMIC_RELAXED,
                                     __HIP_MEMORY_SCOPE_AGENT) < stamp) {
                __builtin_amdgcn_s_sleep(2);
                if (++spins > SPIN_CAP) break;   // hang-breaker: wrong > stuck
            }
        }
        __syncthreads();
        // No acquire fence needed: h addresses are never re-read across steps
        // within a launch, so no cache can hold a stale h line (see header).
    }
}

// ---------------------------------------------------------------------------
// generic contiguous fp32 -> bf16 (n = grid.x * 2048 elems)
__global__ __launch_bounds__(256) void k_cvt_flat(const float* __restrict__ src,
                                                  ushort* __restrict__ dst)
{
    size_t e = ((size_t)blockIdx.x * 256 + threadIdx.x) * 8;
    float4 a = *(const float4*)(src + e);
    float4 b = *(const float4*)(src + e + 4);
    uint4 o;
    o.x = (unsigned)f2bf(a.x) | ((unsigned)f2bf(a.y) << 16);
    o.y = (unsigned)f2bf(a.z) | ((unsigned)f2bf(a.w) << 16);
    o.z = (unsigned)f2bf(b.x) | ((unsigned)f2bf(b.y) << 16);
    o.w = (unsigned)f2bf(b.z) | ((unsigned)f2bf(b.w) << 16);
    *(uint4*)(dst + e) = o;
}

// ---------------------------------------------------------------------------
// encT[b][h][s] = bf16(enc[b][s][h]).  grid (16, 32, 16), block 256.
__global__ __launch_bounds__(256) void k_enc_t(const float* __restrict__ enc,
                                               ushort* __restrict__ encT)
{
    __shared__ float tile[32][33];
    int b = blockIdx.z, s0 = blockIdx.x * 32, h0 = blockIdx.y * 32;
    int tx = threadIdx.x & 31, ty = threadIdx.x >> 5;   // ty 0..7
    const float* src = enc + (size_t)b * 524288;
    #pragma unroll
    for (int i = 0; i < 4; i++) {
        int s = s0 + ty + i * 8;
        tile[ty + i * 8][tx] = src[(size_t)s * 1024 + h0 + tx];
    }
    __syncthreads();
    ushort* dst = encT + (size_t)b * 524288;
    #pragma unroll
    for (int i = 0; i < 4; i++) {
        int h = h0 + ty + i * 8;
        dst[(size_t)h * 512 + s0 + tx] = f2bf(tile[tx][ty + i * 8]);
    }
}

// ---------------------------------------------------------------------------
// bf16 MFMA NT-GEMM: C[M,N] (+)= A @ B^T, all bf16.  64x64 tile, 4 waves;
// wave w computes rows [w*16, w*16+16) x 64 cols. Direct fragment loads.
// A row gather via aIdx (nullable). Batched via blockIdx.z strides.
__global__ __launch_bounds__(256) void k_gemm_bb(
    const ushort* __restrict__ A, int lda, long sA, const int* __restrict__ aIdx,
    const ushort* __restrict__ B, int ldb, long sB,
    ushort* __restrict__ C, int ldc, long sC,
    int M, int K, int accum)
{
    int z = blockIdx.z;
    const ushort* Ab = A + (size_t)z * sA;
    const ushort* Bb = B + (size_t)z * sB;
    ushort* Cb = C + (size_t)z * sC;
    int m0 = blockIdx.y * 64, n0 = blockIdx.x * 64;
    int tid = threadIdx.x, w = tid >> 6, lane = tid & 63;
    int l15 = lane & 15, quad = lane >> 4;
    int am = m0 + w * 16 + l15;
    int ar = (am < M) ? (aIdx ? aIdx[am] : am) : (aIdx ? aIdx[0] : 0);
    const ushort* ap = Ab + (size_t)ar * lda + quad * 8;
    const ushort* bp = Bb + (size_t)(n0 + l15) * ldb + quad * 8;
    f32x4 acc[4] = {{0.f,0.f,0.f,0.f},{0.f,0.f,0.f,0.f},{0.f,0.f,0.f,0.f},{0.f,0.f,0.f,0.f}};
    for (int k0 = 0; k0 < K; k0 += 32) {
        bf16x8 af = *(const bf16x8*)(ap + k0);
        #pragma unroll
        for (int j = 0; j < 4; j++) {
            bf16x8 bfb = *(const bf16x8*)(bp + (size_t)j * 16 * ldb + k0);
            acc[j] = __builtin_amdgcn_mfma_f32_16x16x32_bf16(af, bfb, acc[j], 0, 0, 0);
        }
    }
    #pragma unroll
    for (int j = 0; j < 4; j++)
        #pragma unroll
        for (int r = 0; r < 4; r++) {
            int row = m0 + w * 16 + quad * 4 + r;
            if (row < M) {
                ushort* cp = Cb + (size_t)row * ldc + n0 + j * 16 + l15;
                float v = acc[j][r];
                if (accum) v += bf2f(*cp);
                *cp = f2bf(v);
            }
        }
}

// ---------------------------------------------------------------------------
__global__ __launch_bounds__(256) void k_softmax_b(ushort* __restrict__ sc)
{
    __shared__ float red[4];
    ushort* p = sc + (size_t)blockIdx.x * 512;
    int tid = threadIdx.x;
    float a = bf2f(p[tid]), b = bf2f(p[tid + 256]);
    float m = fmaxf(a, b);
    for (int o = 32; o; o >>= 1) m = fmaxf(m, __shfl_xor(m, o, 64));
    if ((tid & 63) == 0) red[tid >> 6] = m;
    __syncthreads();
    m = fmaxf(fmaxf(red[0], red[1]), fmaxf(red[2], red[3]));
    __syncthreads();
    float ea = __expf(a - m), eb = __expf(b - m);
    float s = ea + eb;
    for (int o = 32; o; o >>= 1) s += __shfl_xor(s, o, 64);
    if ((tid & 63) == 0) red[tid >> 6] = s;
    __syncthreads();
    s = red[0] + red[1] + red[2] + red[3];
    float inv = 1.f / s;
    p[tid] = f2bf(ea * inv);
    p[tid + 256] = f2bf(eb * inv);
}

// ---------------------------------------------------------------------------
__global__ __launch_bounds__(256) void k_tanh_bias_b(ushort* __restrict__ hid,
                                                     const float* __restrict__ b1)
{
    size_t i = (size_t)blockIdx.x * 256 + threadIdx.x;
    hid[i] = f2bf(tanhf(bf2f(hid[i]) + b1[i & 1023]));
}

// ---------------------------------------------------------------------------
__global__ __launch_bounds__(256) void k_loss_b(const ushort* __restrict__ logits,
                                                const float* __restrict__ b2,
                                                const int* __restrict__ dec_out_m,
                                                float* __restrict__ out)
{
    __shared__ float red[4];
    int m = blockIdx.x;
    const ushort* p = logits + (size_t)m * 1024;
    int tid = threadIdx.x;
    float v0 = bf2f(p[tid]) + b2[tid];
    float v1 = bf2f(p[tid + 256]) + b2[tid + 256];
    float v2 = bf2f(p[tid + 512]) + b2[tid + 512];
    float v3 = bf2f(p[tid + 768]) + b2[tid + 768];
    float mx = fmaxf(fmaxf(v0, v1), fmaxf(v2, v3));
    for (int o = 32; o; o >>= 1) mx = fmaxf(mx, __shfl_xor(mx, o, 64));
    if ((tid & 63) == 0) red[tid >> 6] = mx;
    __syncthreads();
    mx = fmaxf(fmaxf(red[0], red[1]), fmaxf(red[2], red[3]));
    __syncthreads();
    float s = __expf(v0 - mx) + __expf(v1 - mx) + __expf(v2 - mx) + __expf(v3 - mx);
    for (int o = 32; o; o >>= 1) s += __shfl_xor(s, o, 64);
    if ((tid & 63) == 0) red[tid >> 6] = s;
    __syncthreads();
    if (tid == 0) {
        float ssum = red[0] + red[1] + red[2] + red[3];
        int tgt = dec_out_m[m];
        float tv = bf2f(p[tgt]) + b2[tgt];
        atomicAdd(out, (mx + logf(ssum) - tv) * (1.0f / 4112.0f));
    }
}

// ---------------------------------------------------------------------------
extern "C" void kernel_launch(void* const* d_in, const int* in_sizes, int n_in,
                              void* d_out, int out_size, void* d_ws, size_t ws_size,
                              hipStream_t stream)
{
    const int*   tokens = (const int*)d_in[0];
    const float* enc    = (const float*)d_in[1];
    const float* emb    = (const float*)d_in[2];
    const float* Wih0   = (const float*)d_in[3];
    const float* Whh0   = (const float*)d_in[4];
    const float* bih0   = (const float*)d_in[5];
    const float* bhh0   = (const float*)d_in[6];
    const float* Wih1   = (const float*)d_in[7];
    const float* Whh1   = (const float*)d_in[8];
    const float* bih1   = (const float*)d_in[9];
    const float* bhh1   = (const float*)d_in[10];
    const float* Wih2   = (const float*)d_in[11];
    const float* Whh2   = (const float*)d_in[12];
    const float* bih2   = (const float*)d_in[13];
    const float* bhh2   = (const float*)d_in[14];
    const float* W1     = (const float*)d_in[15];
    const float* b1     = (const float*)d_in[16];
    const float* W2     = (const float*)d_in[17];
    const float* b2     = (const float*)d_in[18];

    float* out = (float*)d_out;
    if (ws_size < TOTAL_BYTES) { k_fail<<<1, 1, 0, stream>>>(out); return; }

    ushort* wsb  = (ushort*)d_ws;
    ushort* h2h  = wsb + OFF_H2H;
    ushort* sc   = wsb + OFF_SC;
    ushort* ctx  = wsb + OFF_CTX;
    ushort* hid  = wsb + OFF_HID;
    ushort* lg   = wsb + OFF_LG;
    ushort* encB = wsb + OFF_ENCB;
    ushort* encT = wsb + OFF_ENCT;
    ushort* W1b  = wsb + OFF_W1B;
    ushort* W2b  = wsb + OFF_W2B;
    int* dec_in  = (int*)((char*)d_ws + OFF_INT_BYTES);
    int* dec_out = dec_in + 4112;
    int* hsrow   = dec_in + 8224;
    unsigned* arrive = (unsigned*)(dec_in + ARRIVE_I0);

    k_init<<<256, 256, 0, stream>>>(tokens, emb, wsb, out);

    // entire recurrence: one persistent kernel, 259 internal grid barriers
    k_rec_persist<<<NWG, 1024, 0, stream>>>(wsb, Whh0, Wih0, Wih1, Whh1,
                                            Wih2, Whh2, bih0, bhh0, bih1, bhh1,
                                            bih2, bhh2, dec_in, arrive);

    // epilogue conversions (alias over recurrence-only regions)
    k_cvt_flat<<<4096, 256, 0, stream>>>(enc, encB);
    k_enc_t<<<dim3(16, 32, 16), 256, 0, stream>>>(enc, encT);
    k_cvt_flat<<<1024, 256, 0, stream>>>(W1, W1b);
    k_cvt_flat<<<512, 256, 0, stream>>>(W2, W2b);

    // scores[b][t][s] = h2(t) . enc[b,s]
    k_gemm_bb<<<dim3(8, 5, 16), 256, 0, stream>>>(h2h + 16384, 16384, 1024, nullptr,
                                                  encB, 1024, 524288,
                                                  sc, 512, 131584, TT, 1024, 0);
    k_softmax_b<<<4112, 256, 0, stream>>>(sc);
    // ctx[b][t][h] = attn . encT[b][h]
    k_gemm_bb<<<dim3(16, 5, 16), 256, 0, stream>>>(sc, 512, 131584, nullptr,
                                                   encT, 512, 524288,
                                                   ctx, 1024, 263168, TT, 512, 0);
    // hidden = hs @ W1[:, :1024]^T + ctx @ W1[:, 1024:]^T, then tanh(+b1)
    k_gemm_bb<<<dim3(16, 65, 1), 256, 0, stream>>>(h2h, 1024, 0, hsrow,
                                                   W1b, 2048, 0,
                                                   hid, 1024, 0, BT, 1024, 0);
    k_gemm_bb<<<dim3(16, 65, 1), 256, 0, stream>>>(ctx, 1024, 0, nullptr,
                                                   W1b + 1024, 2048, 0,
                                                   hid, 1024, 0, BT, 1024, 1);
    k_tanh_bias_b<<<16448, 256, 0, stream>>>(hid, b1);
    // logits = hidden @ W2^T ; loss
    k_gemm_bb<<<dim3(16, 65, 1), 256, 0, stream>>>(hid, 1024, 0, nullptr,
                                                   W2b, 1024, 0,
                                                   lg, 1024, 0, BT, 1024, 0);
    k_loss_b<<<4112, 256, 0, stream>>>(lg, b2, dec_out, out);
}

// Round 7
// 3083.109 us; speedup vs baseline: 1.3911x; 1.3911x over previous
//
#include <hip/hip_runtime.h>
#include <math.h>

// ---------------------------------------------------------------------------
// Decoder: 3-layer LSTM + dot attention + MLP + CE loss.  B=16, T=257, H=1024.
// Round 11 (= round 9 data path + round 6 barrier topology):
//   - REVERT round 10's af[12]+sched_barrier (FETCH exploded 17x, +50% time).
//     Inner loop = round 9's interleaved load->MFMA (proven 2545 us).
//   - BARRIER: two-phase gather+go (round 6 topology, ran clean there):
//     each WG's tid0 stores its arrive flag; WG0's threads 1..255 each poll
//     ONE flag (single reader per line); WG0 publishes one go word; other
//     WGs poll go with 1 thread each. Replaces round 9's flat poll (65K
//     threads x 256-reader lines = LLC bank serialization ~ the missing
//     ~7 us/step). All flag ops relaxed agent-scope (cache-bypassing).
//   - h stores: relaxed agent-scope atomic write-through (nothing dirty in
//     L2). h loads: normal cached (LLC once per XCD, L2-served after).
//     NO fence: every h address is written once then read once per launch;
//     slots 32KB-aligned; first read strictly follows the producer's
//     vmcnt(0)-drained store via the cache-bypassing barrier.
//   - token prefetch one step ahead (kept from round 10, independent of the
//     regression); bounded spins (hang -> wrong answer, not container kill).
//   - epilogue: unchanged bf16 MFMA NT-GEMM pipeline.
// Workspace: 70.62 MB (< 76.15 MB known-safe).
// ---------------------------------------------------------------------------

namespace {
constexpr int TT = 257;
constexpr int BT = 4112;
constexpr int NSTEP = 259;
constexpr int NWG = 256;

// ushort (bf16) element offsets
constexpr size_t OFF_EMBB = 0;                    // [1024][512] (recurrence only)
constexpr size_t OFF_H0H  = 524288;               // [258][16][1024] (recurrence only)
constexpr size_t OFF_H1H  = 4751360;              // [258][16][1024] (recurrence only)
constexpr size_t OFF_H2H  = 8978432;              // [258][16][1024] (live into epilogue)
// epilogue aliases over embB+h0h+h1h (dead after recurrence):
constexpr size_t OFF_ENCB = 0;                    // [16][512][1024] = 8388608 <= 8978432
constexpr size_t OFF_ENCT = 13205504;             // [16][1024][512]
constexpr size_t OFF_W1B  = 21594112;             // [1024][2048]
constexpr size_t OFF_W2B  = 23691264;             // [1024][1024]
constexpr size_t OFF_SC   = 24739840;             // [16][257][512]
constexpr size_t OFF_CTX  = 26845184;             // [16][257][1024]
constexpr size_t OFF_HID  = 31055872;             // [4112][1024]
constexpr size_t OFF_LG   = OFF_SC;               // alias (sc+ctx dead at logits)
constexpr size_t END_BF   = 35266560;
// int region: dec_in[4112] dec_out[4112] hsrow[4112] pad | arrive[256*32] go
constexpr size_t OFF_INT_BYTES = END_BF * 2;      // 70,533,120
constexpr int    ARRIVE_I0     = 12352;           // int index (128B aligned)
constexpr int    GO_I0         = ARRIVE_I0 + 256 * 32;   // one word after flags
constexpr size_t TOTAL_BYTES   = OFF_INT_BYTES + (GO_I0 + 16) * 4;
constexpr unsigned SPIN_CAP    = 1u << 22;        // hang-breaker (legit wait << this)
}

typedef __attribute__((ext_vector_type(8))) short bf16x8;
typedef __attribute__((ext_vector_type(4))) float f32x4;

__device__ __forceinline__ float bf2f(ushort u) {
    union { unsigned int v; float f; } x; x.v = ((unsigned int)u) << 16; return x.f;
}
__device__ __forceinline__ ushort f2bf(float f) {
    union { float f; unsigned int v; } x; x.f = f;
    return (ushort)((x.v + 0x7fff + ((x.v >> 16) & 1)) >> 16);
}
__device__ __forceinline__ float sigm(float x) { return 1.f / (1.f + __expf(-x)); }

// ---------------------------------------------------------------------------
__global__ void k_fail(float* out) { out[0] = -123456.0f; }

// ---------------------------------------------------------------------------
// init: embB convert, h-history slot0 zeros, dec_in/dec_out/hsrow, flags, out.
// grid 256x256 = 65536 threads. Re-runs per replay (idempotent graph).
__global__ __launch_bounds__(256) void k_init(const int* __restrict__ tokens,
                                              const float* __restrict__ emb,
                                              ushort* __restrict__ wsb,
                                              float* __restrict__ out)
{
    int i = blockIdx.x * 256 + threadIdx.x;          // 0..65535
    int* dec_in  = (int*)((char*)wsb + OFF_INT_BYTES);
    int* dec_out = dec_in + 4112;
    int* hsrow   = dec_in + 8224;
    unsigned* flags = (unsigned*)(dec_in + ARRIVE_I0);
    {   // embB: 524288 elems = 65536 * 8
        size_t e = (size_t)i * 8;
        float4 a = *(const float4*)(emb + e);
        float4 b = *(const float4*)(emb + e + 4);
        uint4 o;
        o.x = (unsigned)f2bf(a.x) | ((unsigned)f2bf(a.y) << 16);
        o.y = (unsigned)f2bf(a.z) | ((unsigned)f2bf(a.w) << 16);
        o.z = (unsigned)f2bf(b.x) | ((unsigned)f2bf(b.y) << 16);
        o.w = (unsigned)f2bf(b.z) | ((unsigned)f2bf(b.w) << 16);
        *(uint4*)(wsb + OFF_EMBB + e) = o;
    }
    if (i < 16384) {                                  // slot 0 = initial zeros
        wsb[OFF_H0H + i] = 0; wsb[OFF_H1H + i] = 0; wsb[OFF_H2H + i] = 0;
    }
    if (i < 4112) {
        int t = i >> 4, b = i & 15;                   // t-major
        dec_in[i] = (t == 0) ? 1 : tokens[b * 256 + (t - 1)];
        int bb = i / 257, tt = i % 257;               // m-order (b-major)
        dec_out[i] = (tt < 256) ? tokens[bb * 256 + tt] : 2;
        hsrow[i] = (tt + 1) * 16 + bb;
    }
    if (i < 256 * 32 + 16) flags[i] = 0u;             // arrive[] + go
    if (i == 0) out[0] = 0.f;
}

// ---------------------------------------------------------------------------
// Persistent fused recurrence. 256 WGs x 1024 thr (16 waves).
// WG u owns units [4u,4u+4) of all 4 gates for all 3 cells. Wave w ->
// (cell, granule range); granule = one 16x16x32 MFMA over a 32-wide K chunk.
// Weights live in wreg[12] (bf16 B-fragments). Diagonal step d: cell0 t=d,
// cell1 t=d-1, cell2 t=d-2. Gather+go grid barrier per step; NO fence.
__global__ __launch_bounds__(1024, 4) void k_rec_persist(
    ushort* __restrict__ wsb,
    const float* __restrict__ Whh0, const float* __restrict__ Wih0,
    const float* __restrict__ Wih1, const float* __restrict__ Whh1,
    const float* __restrict__ Wih2, const float* __restrict__ Whh2,
    const float* __restrict__ bih0, const float* __restrict__ bhh0,
    const float* __restrict__ bih1, const float* __restrict__ bhh1,
    const float* __restrict__ bih2, const float* __restrict__ bhh2,
    const int* __restrict__ dec_in,
    unsigned* __restrict__ arrive, unsigned* __restrict__ go)
{
    __shared__ float p[16][16][17];   // [wave][batch][tile-row], padded

    int tid = threadIdx.x;
    int u = blockIdx.x;                       // 0..255
    int w = tid >> 6, lane = tid & 63, l15 = lane & 15, quad = lane >> 4;

    // wave -> (cell, first granule, count).  cell0: 48 granules (hh0 32 + emb 16)
    // over waves 0-3 (12 each); cell1: 64 (ih1 32 + hh1 32) over waves 4-9
    // (11,11,11,11,10,10); cell2: same over waves 10-15.
    int cell, g0, gcnt;
    if (w < 4)       { cell = 0; g0 = w * 12; gcnt = 12; }
    else if (w < 10) { int wi = w - 4;  cell = 1;
                       g0 = (wi < 4) ? wi * 11 : 44 + (wi - 4) * 10;
                       gcnt = (wi < 4) ? 11 : 10; }
    else             { int wi = w - 10; cell = 2;
                       g0 = (wi < 4) ? wi * 11 : 44 + (wi - 4) * 10;
                       gcnt = (wi < 4) ? 11 : 10; }

    // weight row for tile-row l15: gate gt, unit-sub s4
    int gt = l15 >> 2, s4 = l15 & 3;
    size_t wrow = (size_t)(gt * 1024 + u * 4 + s4);

    // ---- prologue: load + convert this wave's weight fragments (once) ----
    bf16x8 wreg[12];
    #pragma unroll
    for (int gi = 0; gi < 12; ++gi) {
        if (gi < gcnt) {
            int g = g0 + gi;
            const float* src;
            if (cell == 0)
                src = (g < 32) ? Whh0 + wrow * 1024 + (size_t)g * 32
                               : Wih0 + wrow * 1536 + (size_t)(g - 32) * 32;
            else if (cell == 1)
                src = (g < 32) ? Wih1 + wrow * 1024 + (size_t)g * 32
                               : Whh1 + wrow * 1024 + (size_t)(g - 32) * 32;
            else
                src = (g < 32) ? Wih2 + wrow * 1024 + (size_t)g * 32
                               : Whh2 + wrow * 1024 + (size_t)(g - 32) * 32;
            src += quad * 8;
            float4 a = *(const float4*)src;
            float4 b = *(const float4*)(src + 4);
            bf16x8 v;
            v[0] = (short)f2bf(a.x); v[1] = (short)f2bf(a.y);
            v[2] = (short)f2bf(a.z); v[3] = (short)f2bf(a.w);
            v[4] = (short)f2bf(b.x); v[5] = (short)f2bf(b.y);
            v[6] = (short)f2bf(b.z); v[7] = (short)f2bf(b.w);
            wreg[gi] = v;
        }
    }

    // ---- elementwise thread state (tid<192): bias + c in registers ----
    int cellE = tid >> 6;                     // 0..2 for tid<192
    int sub = tid & 63, bE = sub & 15, sE = sub >> 4;
    int colE = u * 4 + sE;
    float bsum[4] = {0.f, 0.f, 0.f, 0.f};
    float cst = 0.f;
    ushort* hE = nullptr;
    int wloE = 0, whiE = 0;
    if (tid < 192) {
        const float* biE = (cellE == 0) ? bih0 : (cellE == 1) ? bih1 : bih2;
        const float* bhE = (cellE == 0) ? bhh0 : (cellE == 1) ? bhh1 : bhh2;
        #pragma unroll
        for (int gq = 0; gq < 4; ++gq)
            bsum[gq] = biE[gq * 1024 + colE] + bhE[gq * 1024 + colE];
        hE = wsb + ((cellE == 0) ? OFF_H0H : (cellE == 1) ? OFF_H1H : OFF_H2H);
        wloE = (cellE == 0) ? 0 : (cellE == 1) ? 4 : 10;
        whiE = (cellE == 0) ? 4 : (cellE == 1) ? 10 : 16;
    }

    ushort* h0h = wsb + OFF_H0H;
    ushort* h1h = wsb + OFF_H1H;
    ushort* h2h = wsb + OFF_H2H;
    const ushort* embB = wsb + OFF_EMBB;
    size_t aoff = (size_t)l15 * 1024 + quad * 8;

    // token prefetch (cell0 waves): tokv holds dec_in for the UPCOMING step
    int tokv = 0;
    if (cell == 0) tokv = dec_in[l15];        // t = 0

    for (int d = 0; d < NSTEP; ++d) {
        int t = d - cell;
        f32x4 acc = {0.f, 0.f, 0.f, 0.f};
        if (t >= 0 && t < TT) {
            const ushort* a0p;
            const ushort* a1p;
            if (cell == 0) {
                a0p = h0h + (size_t)t * 16384 + aoff;  // h0(t-1), slot0 = zeros
                a1p = embB + (size_t)tokv * 512 + quad * 8;
                int tn = (t + 1 < TT) ? (t + 1) : (TT - 1);
                tokv = dec_in[tn * 16 + l15];          // prefetch next token
            } else if (cell == 1) {
                a0p = h0h + (size_t)(t + 1) * 16384 + aoff;  // h0(t)
                a1p = h1h + (size_t)t * 16384 + aoff;        // h1(t-1)
            } else {
                a0p = h1h + (size_t)(t + 1) * 16384 + aoff;  // h1(t)
                a1p = h2h + (size_t)t * 16384 + aoff;        // h2(t-1)
            }
            #pragma unroll
            for (int gi = 0; gi < 12; ++gi) {
                if (gi < gcnt) {
                    int g = g0 + gi;
                    bf16x8 af = (g < 32)
                        ? *(const bf16x8*)(a0p + (size_t)g * 32)
                        : *(const bf16x8*)(a1p + (size_t)(g - 32) * 32);
                    acc = __builtin_amdgcn_mfma_f32_16x16x32_bf16(
                        af, wreg[gi], acc, 0, 0, 0);
                }
            }
        }
        // C/D layout: col=lane&15 (tile row), row=quad*4+reg (batch)
        #pragma unroll
        for (int r = 0; r < 4; ++r) p[w][quad * 4 + r][l15] = acc[r];
        __syncthreads();

        if (tid < 192) {
            int tE = d - cellE;
            if (tE >= 0 && tE < TT) {
                float gv[4];
                #pragma unroll
                for (int gq = 0; gq < 4; ++gq) {
                    float a2 = bsum[gq];
                    for (int ww = wloE; ww < whiE; ++ww)
                        a2 += p[ww][bE][gq * 4 + sE];
                    gv[gq] = a2;
                }
                float ig = sigm(gv[0]), fg = sigm(gv[1]);
                float gg = tanhf(gv[2]), og = sigm(gv[3]);
                cst = fg * cst + ig * gg;
                ushort hus = f2bf(og * tanhf(cst));
                // pack 2 bf16 -> uint; even-sE threads store write-through
                unsigned hi = __shfl_down((unsigned)hus, 16, 64);
                if ((sE & 1) == 0) {
                    unsigned* hp = (unsigned*)(hE + (size_t)(tE + 1) * 16384
                                               + (size_t)bE * 1024 + colE);
                    __hip_atomic_store(hp, (unsigned)hus | (hi << 16),
                                       __ATOMIC_RELAXED, __HIP_MEMORY_SCOPE_AGENT);
                }
            }
        }

        // ---- gather+go grid barrier (round-6 topology), NO fence ----
        asm volatile("s_waitcnt vmcnt(0)" ::: "memory");   // h stores acked @LLC
        __syncthreads();
        unsigned stamp = (unsigned)(d + 1);
        if (u == 0) {
            if (tid > 0 && tid < 256) {         // 255 pollers, 1 line each
                unsigned spins = 0;
                while (__hip_atomic_load(arrive + tid * 32, __ATOMIC_RELAXED,
                                         __HIP_MEMORY_SCOPE_AGENT) < stamp) {
                    if (++spins > SPIN_CAP) break;   // hang-breaker
                }
            }
            __syncthreads();
            if (tid == 0)
                __hip_atomic_store(go, stamp, __ATOMIC_RELAXED,
                                   __HIP_MEMORY_SCOPE_AGENT);
        } else {
            if (tid == 0) {
                __hip_atomic_store(arrive + u * 32, stamp, __ATOMIC_RELAXED,
                                   __HIP_MEMORY_SCOPE_AGENT);
                unsigned spins = 0;
                while (__hip_atomic_load(go, __ATOMIC_RELAXED,
                                         __HIP_MEMORY_SCOPE_AGENT) < stamp) {
                    __builtin_amdgcn_s_sleep(1);
                    if (++spins > SPIN_CAP) break;   // hang-breaker
                }
            }
            __syncthreads();
        }
        // No acquire fence: h addresses are never re-read across steps within
        // a launch, so no cache can hold a stale h line (see header).
    }
}

// ---------------------------------------------------------------------------
// generic contiguous fp32 -> bf16 (n = grid.x * 2048 elems)
__global__ __launch_bounds__(256) void k_cvt_flat(const float* __restrict__ src,
                                                  ushort* __restrict__ dst)
{
    size_t e = ((size_t)blockIdx.x * 256 + threadIdx.x) * 8;
    float4 a = *(const float4*)(src + e);
    float4 b = *(const float4*)(src + e + 4);
    uint4 o;
    o.x = (unsigned)f2bf(a.x) | ((unsigned)f2bf(a.y) << 16);
    o.y = (unsigned)f2bf(a.z) | ((unsigned)f2bf(a.w) << 16);
    o.z = (unsigned)f2bf(b.x) | ((unsigned)f2bf(b.y) << 16);
    o.w = (unsigned)f2bf(b.z) | ((unsigned)f2bf(b.w) << 16);
    *(uint4*)(dst + e) = o;
}

// ---------------------------------------------------------------------------
// encT[b][h][s] = bf16(enc[b][s][h]).  grid (16, 32, 16), block 256.
__global__ __launch_bounds__(256) void k_enc_t(const float* __restrict__ enc,
                                               ushort* __restrict__ encT)
{
    __shared__ float tile[32][33];
    int b = blockIdx.z, s0 = blockIdx.x * 32, h0 = blockIdx.y * 32;
    int tx = threadIdx.x & 31, ty = threadIdx.x >> 5;   // ty 0..7
    const float* src = enc + (size_t)b * 524288;
    #pragma unroll
    for (int i = 0; i < 4; i++) {
        int s = s0 + ty + i * 8;
        tile[ty + i * 8][tx] = src[(size_t)s * 1024 + h0 + tx];
    }
    __syncthreads();
    ushort* dst = encT + (size_t)b * 524288;
    #pragma unroll
    for (int i = 0; i < 4; i++) {
        int h = h0 + ty + i * 8;
        dst[(size_t)h * 512 + s0 + tx] = f2bf(tile[tx][ty + i * 8]);
    }
}

// ---------------------------------------------------------------------------
// bf16 MFMA NT-GEMM: C[M,N] (+)= A @ B^T, all bf16.  64x64 tile, 4 waves;
// wave w computes rows [w*16, w*16+16) x 64 cols. Direct fragment loads.
// A row gather via aIdx (nullable). Batched via blockIdx.z strides.
__global__ __launch_bounds__(256) void k_gemm_bb(
    const ushort* __restrict__ A, int lda, long sA, const int* __restrict__ aIdx,
    const ushort* __restrict__ B, int ldb, long sB,
    ushort* __restrict__ C, int ldc, long sC,
    int M, int K, int accum)
{
    int z = blockIdx.z;
    const ushort* Ab = A + (size_t)z * sA;
    const ushort* Bb = B + (size_t)z * sB;
    ushort* Cb = C + (size_t)z * sC;
    int m0 = blockIdx.y * 64, n0 = blockIdx.x * 64;
    int tid = threadIdx.x, w = tid >> 6, lane = tid & 63;
    int l15 = lane & 15, quad = lane >> 4;
    int am = m0 + w * 16 + l15;
    int ar = (am < M) ? (aIdx ? aIdx[am] : am) : (aIdx ? aIdx[0] : 0);
    const ushort* ap = Ab + (size_t)ar * lda + quad * 8;
    const ushort* bp = Bb + (size_t)(n0 + l15) * ldb + quad * 8;
    f32x4 acc[4] = {{0.f,0.f,0.f,0.f},{0.f,0.f,0.f,0.f},{0.f,0.f,0.f,0.f},{0.f,0.f,0.f,0.f}};
    for (int k0 = 0; k0 < K; k0 += 32) {
        bf16x8 af = *(const bf16x8*)(ap + k0);
        #pragma unroll
        for (int j = 0; j < 4; j++) {
            bf16x8 bfb = *(const bf16x8*)(bp + (size_t)j * 16 * ldb + k0);
            acc[j] = __builtin_amdgcn_mfma_f32_16x16x32_bf16(af, bfb, acc[j], 0, 0, 0);
        }
    }
    #pragma unroll
    for (int j = 0; j < 4; j++)
        #pragma unroll
        for (int r = 0; r < 4; r++) {
            int row = m0 + w * 16 + quad * 4 + r;
            if (row < M) {
                ushort* cp = Cb + (size_t)row * ldc + n0 + j * 16 + l15;
                float v = acc[j][r];
                if (accum) v += bf2f(*cp);
                *cp = f2bf(v);
            }
        }
}

// ---------------------------------------------------------------------------
__global__ __launch_bounds__(256) void k_softmax_b(ushort* __restrict__ sc)
{
    __shared__ float red[4];
    ushort* p = sc + (size_t)blockIdx.x * 512;
    int tid = threadIdx.x;
    float a = bf2f(p[tid]), b = bf2f(p[tid + 256]);
    float m = fmaxf(a, b);
    for (int o = 32; o; o >>= 1) m = fmaxf(m, __shfl_xor(m, o, 64));
    if ((tid & 63) == 0) red[tid >> 6] = m;
    __syncthreads();
    m = fmaxf(fmaxf(red[0], red[1]), fmaxf(red[2], red[3]));
    __syncthreads();
    float ea = __expf(a - m), eb = __expf(b - m);
    float s = ea + eb;
    for (int o = 32; o; o >>= 1) s += __shfl_xor(s, o, 64);
    if ((tid & 63) == 0) red[tid >> 6] = s;
    __syncthreads();
    s = red[0] + red[1] + red[2] + red[3];
    float inv = 1.f / s;
    p[tid] = f2bf(ea * inv);
    p[tid + 256] = f2bf(eb * inv);
}

// ---------------------------------------------------------------------------
__global__ __launch_bounds__(256) void k_tanh_bias_b(ushort* __restrict__ hid,
                                                     const float* __restrict__ b1)
{
    size_t i = (size_t)blockIdx.x * 256 + threadIdx.x;
    hid[i] = f2bf(tanhf(bf2f(hid[i]) + b1[i & 1023]));
}

// ---------------------------------------------------------------------------
__global__ __launch_bounds__(256) void k_loss_b(const ushort* __restrict__ logits,
                                                const float* __restrict__ b2,
                                                const int* __restrict__ dec_out_m,
                                                float* __restrict__ out)
{
    __shared__ float red[4];
    int m = blockIdx.x;
    const ushort* p = logits + (size_t)m * 1024;
    int tid = threadIdx.x;
    float v0 = bf2f(p[tid]) + b2[tid];
    float v1 = bf2f(p[tid + 256]) + b2[tid + 256];
    float v2 = bf2f(p[tid + 512]) + b2[tid + 512];
    float v3 = bf2f(p[tid + 768]) + b2[tid + 768];
    float mx = fmaxf(fmaxf(v0, v1), fmaxf(v2, v3));
    for (int o = 32; o; o >>= 1) mx = fmaxf(mx, __shfl_xor(mx, o, 64));
    if ((tid & 63) == 0) red[tid >> 6] = mx;
    __syncthreads();
    mx = fmaxf(fmaxf(red[0], red[1]), fmaxf(red[2], red[3]));
    __syncthreads();
    float s = __expf(v0 - mx) + __expf(v1 - mx) + __expf(v2 - mx) + __expf(v3 - mx);
    for (int o = 32; o; o >>= 1) s += __shfl_xor(s, o, 64);
    if ((tid & 63) == 0) red[tid >> 6] = s;
    __syncthreads();
    if (tid == 0) {
        float ssum = red[0] + red[1] + red[2] + red[3];
        int tgt = dec_out_m[m];
        float tv = bf2f(p[tgt]) + b2[tgt];
        atomicAdd(out, (mx + logf(ssum) - tv) * (1.0f / 4112.0f));
    }
}

// ---------------------------------------------------------------------------
extern "C" void kernel_launch(void* const* d_in, const int* in_sizes, int n_in,
                              void* d_out, int out_size, void* d_ws, size_t ws_size,
                              hipStream_t stream)
{
    const int*   tokens = (const int*)d_in[0];
    const float* enc    = (const float*)d_in[1];
    const float* emb    = (const float*)d_in[2];
    const float* Wih0   = (const float*)d_in[3];
    const float* Whh0   = (const float*)d_in[4];
    const float* bih0   = (const float*)d_in[5];
    const float* bhh0   = (const float*)d_in[6];
    const float* Wih1   = (const float*)d_in[7];
    const float* Whh1   = (const float*)d_in[8];
    const float* bih1   = (const float*)d_in[9];
    const float* bhh1   = (const float*)d_in[10];
    const float* Wih2   = (const float*)d_in[11];
    const float* Whh2   = (const float*)d_in[12];
    const float* bih2   = (const float*)d_in[13];
    const float* bhh2   = (const float*)d_in[14];
    const float* W1     = (const float*)d_in[15];
    const float* b1     = (const float*)d_in[16];
    const float* W2     = (const float*)d_in[17];
    const float* b2     = (const float*)d_in[18];

    float* out = (float*)d_out;
    if (ws_size < TOTAL_BYTES) { k_fail<<<1, 1, 0, stream>>>(out); return; }

    ushort* wsb  = (ushort*)d_ws;
    ushort* h2h  = wsb + OFF_H2H;
    ushort* sc   = wsb + OFF_SC;
    ushort* ctx  = wsb + OFF_CTX;
    ushort* hid  = wsb + OFF_HID;
    ushort* lg   = wsb + OFF_LG;
    ushort* encB = wsb + OFF_ENCB;
    ushort* encT = wsb + OFF_ENCT;
    ushort* W1b  = wsb + OFF_W1B;
    ushort* W2b  = wsb + OFF_W2B;
    int* dec_in  = (int*)((char*)d_ws + OFF_INT_BYTES);
    int* dec_out = dec_in + 4112;
    int* hsrow   = dec_in + 8224;
    unsigned* arrive = (unsigned*)(dec_in + ARRIVE_I0);
    unsigned* go     = (unsigned*)(dec_in + GO_I0);

    k_init<<<256, 256, 0, stream>>>(tokens, emb, wsb, out);

    // entire recurrence: one persistent kernel, 259 internal grid barriers
    k_rec_persist<<<NWG, 1024, 0, stream>>>(wsb, Whh0, Wih0, Wih1, Whh1,
                                            Wih2, Whh2, bih0, bhh0, bih1, bhh1,
                                            bih2, bhh2, dec_in, arrive, go);

    // epilogue conversions (alias over recurrence-only regions)
    k_cvt_flat<<<4096, 256, 0, stream>>>(enc, encB);
    k_enc_t<<<dim3(16, 32, 16), 256, 0, stream>>>(enc, encT);
    k_cvt_flat<<<1024, 256, 0, stream>>>(W1, W1b);
    k_cvt_flat<<<512, 256, 0, stream>>>(W2, W2b);

    // scores[b][t][s] = h2(t) . enc[b,s]
    k_gemm_bb<<<dim3(8, 5, 16), 256, 0, stream>>>(h2h + 16384, 16384, 1024, nullptr,
                                                  encB, 1024, 524288,
                                                  sc, 512, 131584, TT, 1024, 0);
    k_softmax_b<<<4112, 256, 0, stream>>>(sc);
    // ctx[b][t][h] = attn . encT[b][h]
    k_gemm_bb<<<dim3(16, 5, 16), 256, 0, stream>>>(sc, 512, 131584, nullptr,
                                                   encT, 512, 524288,
                                                   ctx, 1024, 263168, TT, 512, 0);
    // hidden = hs @ W1[:, :1024]^T + ctx @ W1[:, 1024:]^T, then tanh(+b1)
    k_gemm_bb<<<dim3(16, 65, 1), 256, 0, stream>>>(h2h, 1024, 0, hsrow,
                                                   W1b, 2048, 0,
                                                   hid, 1024, 0, BT, 1024, 0);
    k_gemm_bb<<<dim3(16, 65, 1), 256, 0, stream>>>(ctx, 1024, 0, nullptr,
                                                   W1b + 1024, 2048, 0,
                                                   hid, 1024, 0, BT, 1024, 1);
    k_tanh_bias_b<<<16448, 256, 0, stream>>>(hid, b1);
    // logits = hidden @ W2^T ; loss
    k_gemm_bb<<<dim3(16, 65, 1), 256, 0, stream>>>(hid, 1024, 0, nullptr,
                                                   W2b, 1024, 0,
                                                   lg, 1024, 0, BT, 1024, 0);
    k_loss_b<<<4112, 256, 0, stream>>>(lg, b2, dec_out, out);
}